// Round 6
// baseline (3676.471 us; speedup 1.0000x reference)
//
#include <hip/hip_runtime.h>
#include <hip/hip_bf16.h>
#include <math.h>

typedef __attribute__((ext_vector_type(8))) short bf16x8;
typedef __attribute__((ext_vector_type(4))) float f32x4;

constexpr int NPTS = 65536;
constexpr int ENC  = 512;
constexpr int P    = 4096;
constexpr int JD   = 1024;   // 2*ENC
constexpr int ID   = 8192;   // 2*P
constexpr int CH   = 8192;   // point chunk
constexpr int NCH  = NPTS / CH;
constexpr int LDK  = 8192;   // k-stride (elements) of all GEMM operand rows

constexpr float INV_R   = 20.0f;                  // 1/0.05
constexpr float INV2PI  = 0.15915494309189535f;
constexpr float SQRT_D  = 22.627416997969522f;    // sqrt(512)

__device__ __forceinline__ unsigned short f2bf(float f) {
    unsigned int u = __float_as_uint(f);
    u = (u + 0x7FFFu + ((u >> 16) & 1u)) >> 16;
    return (unsigned short)u;
}

// phases are up to ~±350 revolutions: must fract-reduce before v_sin/v_cos
__device__ __forceinline__ void sincos_rev(float p, float* s, float* c) {
    float r = p * INV2PI;
    r = r - floorf(r);                 // [0,1)
    *s = __builtin_amdgcn_sinf(r);     // sin(2*pi*r)
    *c = __builtin_amdgcn_cosf(r);
}

__device__ __forceinline__ void gload16(const void* g, void* l) {
    __builtin_amdgcn_global_load_lds(
        (const __attribute__((address_space(1))) unsigned int*)g,
        (__attribute__((address_space(3))) unsigned int*)l, 16, 0, 0);
}

// ---------------- gen transposed e-matrices (phase A) ----------------
__global__ __launch_bounds__(256)
void gen_t(const float* __restrict__ pts, const float* __restrict__ A,
           const float* __restrict__ B, unsigned short* __restrict__ eAT,
           unsigned short* __restrict__ eBT, int n0) {
    int idx = blockIdx.x * 256 + threadIdx.x;
    int nh  = idx & (CH / 2 - 1);      // 4096 pairs
    int r   = idx >> 12;               // row in [0, 4608): first 512 = A rows
    int nl  = nh * 2;
    int n   = n0 + nl;
    float x0a = pts[n * 3 + 0], x1a = pts[n * 3 + 1], x2a = pts[n * 3 + 2];
    float x0b = pts[n * 3 + 3], x1b = pts[n * 3 + 4], x2b = pts[n * 3 + 5];
    float w0, w1, w2;
    unsigned short *dc, *dsn;
    if (r < ENC) {
        w0 = A[r]; w1 = A[ENC + r]; w2 = A[2 * ENC + r];
        dc  = eAT + (size_t)r * CH + nl;
        dsn = eAT + (size_t)(r + ENC) * CH + nl;
    } else {
        int i = r - ENC;
        w0 = B[i]; w1 = B[P + i]; w2 = B[2 * P + i];
        dc  = eBT + (size_t)i * CH + nl;
        dsn = eBT + (size_t)(i + P) * CH + nl;
    }
    float pa = (x0a * w0 + x1a * w1 + x2a * w2) * INV_R;
    float pb = (x0b * w0 + x1b * w1 + x2b * w2) * INV_R;
    float sa, ca, sb, cb;
    sincos_rev(pa, &sa, &ca);
    sincos_rev(pb, &sb, &cb);
    ushort2 vc; vc.x = f2bf(ca); vc.y = f2bf(cb);
    ushort2 vs; vs.x = f2bf(sa); vs.y = f2bf(sb);
    *(ushort2*)dc  = vc;
    *(ushort2*)dsn = vs;
}

// ---------------- gen eB row-major (phase C) ----------------
__global__ __launch_bounds__(256)
void gen_b(const float* __restrict__ pts, const float* __restrict__ B,
           unsigned short* __restrict__ eB, int n0) {
    int idx = blockIdx.x * 256 + threadIdx.x;
    int ih = idx & 2047;
    int ln = idx >> 11;
    int i  = ih * 2;
    int n  = n0 + ln;
    float x0 = pts[n * 3 + 0], x1 = pts[n * 3 + 1], x2 = pts[n * 3 + 2];
    float p0 = (x0 * B[i]     + x1 * B[P + i]     + x2 * B[2 * P + i])     * INV_R;
    float p1 = (x0 * B[i + 1] + x1 * B[P + i + 1] + x2 * B[2 * P + i + 1]) * INV_R;
    float s0, c0, s1, c1;
    sincos_rev(p0, &s0, &c0);
    sincos_rev(p1, &s1, &c1);
    ushort2 vc; vc.x = f2bf(c0); vc.y = f2bf(c1);
    ushort2 vs; vs.x = f2bf(s0); vs.y = f2bf(s1);
    *(ushort2*)(eB + (size_t)ln * ID + i)     = vc;
    *(ushort2*)(eB + (size_t)ln * ID + P + i) = vs;
}

// ---------------- high-occupancy GEMM: C[m][n] (+)= sum_k A[m][k]*B[n][k] --
// 128x128 tile, 256 thr = 4 waves of 64x64, BK=32, triple-buffered 48 KiB LDS
// -> 3 blocks/CU (12 waves). Cross-BLOCK waves are not barrier-synced: one
// block's ds_read/stage window overlaps another block's MFMA window (the
// m97/m114 overlap mechanism). Counted vmcnt(4) (prefetch depth 2, never 0
// mid-loop), one barrier per K-tile, setprio around MFMA.
// LDS rows are 32 elem (64 B): swizzle slot = q ^ ((row>>1)&3) gives 2-way
// (free) bank access on reads; staged via pre-swizzled global source.
template <bool ACCUM>
__global__ __launch_bounds__(256, 3)
void gemm_hp(const unsigned short* __restrict__ Ag,
             const unsigned short* __restrict__ Bg,
             float* __restrict__ C, int ldc, int K, int beta) {
    constexpr int BSZ = 8192;              // elements per K-tile buffer (A+B)
    __shared__ __align__(16) unsigned short lds[3 * BSZ];   // 48 KiB

    const int tid  = threadIdx.x;
    const int wave = tid >> 6, lane = tid & 63;
    const int mr = lane & 15, q = lane >> 4;
    const int wm = (wave & 1) * 64, wn = (wave >> 1) * 64;
    const int NT = K >> 5;                 // K-tiles of 32

    // XCD-chunked bijective swizzle (nwg = 512, divisible by 8)
    const int gx   = gridDim.x;
    const int nwg  = gx * gridDim.y;
    const int flat = blockIdx.y * gx + blockIdx.x;
    const int swz  = (flat & 7) * (nwg >> 3) + (flat >> 3);
    const int m0   = (swz % gx) * 128;
    const int n0   = (swz / gx) * 128;

    // staging: 4 issues/K-tile (2 A-halves, 2 B-halves), each 256thr x 16B
    // = 64 rows x 64B. Pre-swizzled source chunk u = (tid&3) ^ ((srow>>1)&3).
    const int srow = tid >> 2;
    const int u16  = ((tid & 3) ^ ((srow >> 1) & 3)) * 16;
    const char* aG = (const char*)Ag;
    const char* bG = (const char*)Bg;
    size_t aoff[2], boff[2];
#pragma unroll
    for (int j = 0; j < 2; ++j) {
        aoff[j] = (size_t)(m0 + j * 64 + srow) * (LDK * 2) + u16;
        boff[j] = (size_t)(n0 + j * 64 + srow) * (LDK * 2) + u16;
    }

    unsigned short* bufC  = lds;
    unsigned short* bufN  = lds + BSZ;
    unsigned short* bufN2 = lds + 2 * BSZ;

    // issues 0,1 = A halves; 2,3 = B halves (2048 elem each)
    auto stage = [&](int idx, unsigned short* buf, size_t kB) {
        if (idx < 2)
            gload16(aG + aoff[idx] + kB, buf + idx * 2048 + tid * 8);
        else
            gload16(bG + boff[idx - 2] + kB,
                    buf + 4096 + (idx - 2) * 2048 + tid * 8);
    };

    f32x4 acc[4][4];
#pragma unroll
    for (int a = 0; a < 4; ++a)
#pragma unroll
        for (int b = 0; b < 4; ++b) acc[a][b] = (f32x4){0.f, 0.f, 0.f, 0.f};

    // prologue: tiles 0,1 in flight; wait tile 0 only (vmcnt(4))
#pragma unroll
    for (int i = 0; i < 4; ++i) stage(i, bufC, 0);
#pragma unroll
    for (int i = 0; i < 4; ++i) stage(i, bufN, 64);
    asm volatile("s_waitcnt vmcnt(4)" ::: "memory");
    __builtin_amdgcn_s_barrier();
    __builtin_amdgcn_sched_barrier(0);

    // per-lane constant fragment slot: row&3-bits reduce to mr
    const int sl = ((q ^ ((mr >> 1) & 3)) * 8);

    size_t kPre = 128;                 // byte k-offset of tile kt+2
#pragma unroll 1
    for (int kt = 0; kt < NT; ++kt) {
        const bool pf = (kt + 2 < NT);
        bf16x8 af[4], bfr[4];
#pragma unroll
        for (int mi = 0; mi < 4; ++mi) {
            int m = wm + mi * 16 + mr;
            af[mi] = *(const bf16x8*)(bufC + m * 32 + sl);
        }
#pragma unroll
        for (int ni = 0; ni < 4; ++ni) {
            int n = wn + ni * 16 + mr;
            bfr[ni] = *(const bf16x8*)(bufC + 4096 + n * 32 + sl);
        }
        if (pf) {
#pragma unroll
            for (int i = 0; i < 4; ++i) stage(i, bufN2, kPre);
        }
        __builtin_amdgcn_s_setprio(1);
#pragma unroll
        for (int mi = 0; mi < 4; ++mi)
#pragma unroll
            for (int ni = 0; ni < 4; ++ni)
                acc[mi][ni] = __builtin_amdgcn_mfma_f32_16x16x32_bf16(
                    af[mi], bfr[ni], acc[mi][ni], 0, 0, 0);
        __builtin_amdgcn_s_setprio(0);
        // counted end-of-tile wait: kt+1's 4 loads landed; kt+2's 4 in flight
        if (pf)                    asm volatile("s_waitcnt vmcnt(4)" ::: "memory");
        else if (kt + 1 < NT)      asm volatile("s_waitcnt vmcnt(0)" ::: "memory");
        __builtin_amdgcn_s_barrier();
        __builtin_amdgcn_sched_barrier(0);
        unsigned short* t = bufC; bufC = bufN; bufN = bufN2; bufN2 = t;
        kPre += 64;
    }

    // C/D layout: col = lane&15, row = (lane>>4)*4 + reg
#pragma unroll
    for (int mi = 0; mi < 4; ++mi)
#pragma unroll
        for (int ni = 0; ni < 4; ++ni)
#pragma unroll
            for (int r = 0; r < 4; ++r) {
                int m = m0 + wm + mi * 16 + q * 4 + r;
                int n = n0 + wn + ni * 16 + mr;
                size_t off = (size_t)m * ldc + n;
                float v = acc[mi][ni][r];
                if (ACCUM) { if (beta) v += C[off]; }
                C[off] = v;
            }
}

// ---------------- MT fp32 -> bf16 ----------------
__global__ __launch_bounds__(256)
void cvt(const float* __restrict__ src, unsigned short* __restrict__ dst) {
    int idx = blockIdx.x * 256 + threadIdx.x;
    float4 v = ((const float4*)src)[idx];
    ushort4 o;
    o.x = f2bf(v.x); o.y = f2bf(v.y); o.z = f2bf(v.z); o.w = f2bf(v.w);
    ((ushort4*)dst)[idx] = o;
}

// ---------------- epilogue: re/im, row norm, scale (in place on d_out) ----
__global__ __launch_bounds__(256)
void epi(float* __restrict__ out, const float* __restrict__ pts,
         const float* __restrict__ A) {
    int n = blockIdx.x;
    int t = threadIdx.x;
    float x0 = pts[n * 3 + 0], x1 = pts[n * 3 + 1], x2 = pts[n * 3 + 2];
    float* row = out + (size_t)n * JD;
    float reA[2], imA[2];
    float ssum = 0.f;
#pragma unroll
    for (int u = 0; u < 2; ++u) {
        int j = t + u * 256;
        float pa = (x0 * A[j] + x1 * A[ENC + j] + x2 * A[2 * ENC + j]) * INV_R;
        float s, c;
        sincos_rev(pa, &s, &c);
        float gc = row[j], gs = row[ENC + j];
        float re = gc * c + gs * s;
        float im = gs * c - gc * s;
        reA[u] = re; imA[u] = im;
        ssum += re * re + im * im;
    }
#pragma unroll
    for (int off = 32; off > 0; off >>= 1) ssum += __shfl_down(ssum, off);
    __shared__ float red[4];
    if ((t & 63) == 0) red[t >> 6] = ssum;
    __syncthreads();
    float tot = red[0] + red[1] + red[2] + red[3];
    float scale = SQRT_D / sqrtf(tot);
#pragma unroll
    for (int u = 0; u < 2; ++u) {
        int j = t + u * 256;
        row[j]       = reA[u] * scale;
        row[ENC + j] = imA[u] * scale;
    }
}

extern "C" void kernel_launch(void* const* d_in, const int* in_sizes, int n_in,
                              void* d_out, int out_size, void* d_ws, size_t ws_size,
                              hipStream_t stream) {
    const float* pts = (const float*)d_in[0];
    const float* A   = (const float*)d_in[1];
    const float* B   = (const float*)d_in[2];
    float* out = (float*)d_out;
    char* ws = (char*)d_ws;

    // ws layout (~199 MiB):
    //   [0, 16M)          eAT  [1024][8192] bf16   (phase A)  / eB [8192][8192] (phase C, spans both)
    //   [16M, 151M)       eBT  [8192][8192] bf16   (phase A)
    //   [151M, 183M)      MTf  [1024][8192] fp32
    //   [183M, 199M)      MTb  [1024][8192] bf16
    unsigned short* eAT = (unsigned short*)ws;
    unsigned short* eBT = (unsigned short*)(ws + (size_t)JD * CH * 2);
    unsigned short* eBw = (unsigned short*)ws;
    size_t offMT = (size_t)(JD + ID) * CH * 2;
    float* MTf = (float*)(ws + offMT);
    unsigned short* MTb = (unsigned short*)(ws + offMT + (size_t)JD * ID * 4);

    for (int c = 0; c < NCH; ++c) {
        gen_t<<<dim3(73728), 256, 0, stream>>>(pts, A, B, eAT, eBT, c * CH);
        // MT[j][i] += eAT[j][:] . eBT[i][:]  (M=1024: 8 tiles, N=8192: 64 -> 512 WGs)
        gemm_hp<true><<<dim3(8, 64), 256, 0, stream>>>(
            eAT, eBT, MTf, ID, CH, c);
    }
    cvt<<<dim3(8192), 256, 0, stream>>>(MTf, MTb);
    for (int c = 0; c < NCH; ++c) {
        gen_b<<<dim3(65536), 256, 0, stream>>>(pts, B, eBw, c * CH);
        // G[ln][j] = eB[ln][:] . MTb[j][:]   (M=8192: 64 tiles, N=1024: 8 -> 512 WGs)
        gemm_hp<false><<<dim3(64, 8), 256, 0, stream>>>(
            eBw, MTb, out + (size_t)c * CH * JD, JD, ID, 0);
    }
    epi<<<dim3(NPTS), 256, 0, stream>>>(out, pts, A);
}

// Round 7
// 2858.275 us; speedup vs baseline: 1.2863x; 1.2863x over previous
//
#include <hip/hip_runtime.h>
#include <hip/hip_bf16.h>
#include <math.h>

typedef __attribute__((ext_vector_type(8))) short bf16x8;
typedef __attribute__((ext_vector_type(4))) float f32x4;
typedef __attribute__((ext_vector_type(4))) int   i32x4;

constexpr int NPTS = 65536;
constexpr int ENC  = 512;
constexpr int P    = 4096;
constexpr int JD   = 1024;   // 2*ENC
constexpr int ID   = 8192;   // 2*P
constexpr int CH   = 8192;   // point chunk
constexpr int NCH  = NPTS / CH;
constexpr int LDK  = 8192;   // k-stride (elements) of all GEMM operand rows

constexpr float INV_R   = 20.0f;                  // 1/0.05
constexpr float INV2PI  = 0.15915494309189535f;
constexpr float SQRT_D  = 22.627416997969522f;    // sqrt(512)
constexpr float INV_Q2  = 1.0f / (127.0f * 127.0f);

__device__ __forceinline__ unsigned short f2bf(float f) {
    unsigned int u = __float_as_uint(f);
    u = (u + 0x7FFFu + ((u >> 16) & 1u)) >> 16;
    return (unsigned short)u;
}

// phases are up to ~±350 revolutions: must fract-reduce before v_sin/v_cos
__device__ __forceinline__ void sincos_rev(float p, float* s, float* c) {
    float r = p * INV2PI;
    r = r - floorf(r);                 // [0,1)
    *s = __builtin_amdgcn_sinf(r);     // sin(2*pi*r)
    *c = __builtin_amdgcn_cosf(r);
}

__device__ __forceinline__ void gload16(const void* g, void* l) {
    __builtin_amdgcn_global_load_lds(
        (const __attribute__((address_space(1))) unsigned int*)g,
        (__attribute__((address_space(3))) unsigned int*)l, 16, 0, 0);
}

// ---------------- gen transposed e-matrices, int8 (phase A) ----------------
// eAT8 [1024][CH], eBT8 [8192][CH] int8 (q = rint(127*v)); each thread:
// one row r, two consecutive points.
__global__ __launch_bounds__(256)
void gen_t(const float* __restrict__ pts, const float* __restrict__ A,
           const float* __restrict__ B, signed char* __restrict__ eAT,
           signed char* __restrict__ eBT, int n0) {
    int idx = blockIdx.x * 256 + threadIdx.x;
    int nh  = idx & (CH / 2 - 1);      // 4096 pairs
    int r   = idx >> 12;               // row in [0, 4608): first 512 = A rows
    int nl  = nh * 2;
    int n   = n0 + nl;
    float x0a = pts[n * 3 + 0], x1a = pts[n * 3 + 1], x2a = pts[n * 3 + 2];
    float x0b = pts[n * 3 + 3], x1b = pts[n * 3 + 4], x2b = pts[n * 3 + 5];
    float w0, w1, w2;
    signed char *dc, *dsn;
    if (r < ENC) {
        w0 = A[r]; w1 = A[ENC + r]; w2 = A[2 * ENC + r];
        dc  = eAT + (size_t)r * CH + nl;
        dsn = eAT + (size_t)(r + ENC) * CH + nl;
    } else {
        int i = r - ENC;
        w0 = B[i]; w1 = B[P + i]; w2 = B[2 * P + i];
        dc  = eBT + (size_t)i * CH + nl;
        dsn = eBT + (size_t)(i + P) * CH + nl;
    }
    float pa = (x0a * w0 + x1a * w1 + x2a * w2) * INV_R;
    float pb = (x0b * w0 + x1b * w1 + x2b * w2) * INV_R;
    float sa, ca, sb, cb;
    sincos_rev(pa, &sa, &ca);
    sincos_rev(pb, &sb, &cb);
    char2 vc, vs;
    vc.x = (signed char)__float2int_rn(ca * 127.0f);
    vc.y = (signed char)__float2int_rn(cb * 127.0f);
    vs.x = (signed char)__float2int_rn(sa * 127.0f);
    vs.y = (signed char)__float2int_rn(sb * 127.0f);
    *(char2*)dc  = vc;
    *(char2*)dsn = vs;
}

// ---------------- gen eB row-major bf16 (phase C) ----------------
__global__ __launch_bounds__(256)
void gen_b(const float* __restrict__ pts, const float* __restrict__ B,
           unsigned short* __restrict__ eB, int n0) {
    int idx = blockIdx.x * 256 + threadIdx.x;
    int ih = idx & 2047;
    int ln = idx >> 11;
    int i  = ih * 2;
    int n  = n0 + ln;
    float x0 = pts[n * 3 + 0], x1 = pts[n * 3 + 1], x2 = pts[n * 3 + 2];
    float p0 = (x0 * B[i]     + x1 * B[P + i]     + x2 * B[2 * P + i])     * INV_R;
    float p1 = (x0 * B[i + 1] + x1 * B[P + i + 1] + x2 * B[2 * P + i + 1]) * INV_R;
    float s0, c0, s1, c1;
    sincos_rev(p0, &s0, &c0);
    sincos_rev(p1, &s1, &c1);
    ushort2 vc; vc.x = f2bf(c0); vc.y = f2bf(c1);
    ushort2 vs; vs.x = f2bf(s0); vs.y = f2bf(s1);
    *(ushort2*)(eB + (size_t)ln * ID + i)     = vc;
    *(ushort2*)(eB + (size_t)ln * ID + P + i) = vs;
}

// ---------------- GEMM1 int8: C[m][n] (+)= sum_k A[m][k]*B[n][k] -----------
// R1/R3-proven structure at 2x work per K-tile via i8 BK=128:
// 128x256 tile, 512 thr = 8 waves of 64x64, triple-buffered 144 KiB LDS,
// prefetch depth 2, counted vmcnt(6) (never 0 mid-loop), one barrier/K-tile.
// Rows are 128 B (8 x 16B slots) exactly as the bf16 BK=64 version ->
// identical swizzle algebra (slot ^= row&7), identical issue count.
// mfma_i32_16x16x64_i8: lane (mr,q) holds 16 consecutive i8 at k=q*16.
// i32 accumulation is exact and order-independent (beta-chained chunks).
__global__ __launch_bounds__(512, 2)
void gemm_i8(const signed char* __restrict__ Ag,
             const signed char* __restrict__ Bg,
             int* __restrict__ C, int ldc, int beta) {
    constexpr int BSZB = (128 + 256) * 128;        // 48 KiB per K-tile buffer
    constexpr int NT   = 8192 / 128;               // 64 K-tiles
    __shared__ __align__(16) signed char lds[3 * BSZB];   // 144 KiB

    const int tid  = threadIdx.x;
    const int wave = tid >> 6, lane = tid & 63;
    const int mr = lane & 15, q = lane >> 4;
    const int srow = tid >> 3, sslot = tid & 7;
    const int wm = (wave & 1) * 64, wn = (wave >> 1) * 64;

    // XCD-chunked bijective swizzle (nwg = 256)
    const int gx   = gridDim.x;
    const int nwg  = gx * gridDim.y;
    const int flat = blockIdx.y * gx + blockIdx.x;
    const int swz  = (flat & 7) * (nwg >> 3) + (flat >> 3);
    const int m0   = (swz % gx) * 128;
    const int n0   = (swz / gx) * 256;

    const char* aG = (const char*)Ag;
    const char* bG = (const char*)Bg;
    const int ssw = (sslot ^ (srow & 7)) * 16;     // pre-swizzled 16B slot
    size_t aoff[2], boff[4];
#pragma unroll
    for (int j = 0; j < 2; ++j)
        aoff[j] = (size_t)(m0 + j * 64 + srow) * LDK + ssw;
#pragma unroll
    for (int j = 0; j < 4; ++j)
        boff[j] = (size_t)(n0 + j * 64 + srow) * LDK + ssw;

    signed char* bufC  = lds;
    signed char* bufN  = lds + BSZB;
    signed char* bufN2 = lds + 2 * BSZB;

    // issues 0,1 = A halves (64 rows x 128B); 2..5 = B quarters
    auto stage = [&](int idx, signed char* buf, size_t kB) {
        if (idx < 2)
            gload16(aG + aoff[idx] + kB, buf + idx * 8192 + tid * 16);
        else
            gload16(bG + boff[idx - 2] + kB,
                    buf + 16384 + (idx - 2) * 8192 + tid * 16);
    };

    i32x4 acc[4][4];
#pragma unroll
    for (int a = 0; a < 4; ++a)
#pragma unroll
        for (int b = 0; b < 4; ++b) acc[a][b] = (i32x4){0, 0, 0, 0};

    // prologue: tiles 0,1 in flight; wait tile 0 only (vmcnt(6))
#pragma unroll
    for (int i = 0; i < 6; ++i) stage(i, bufC, 0);
#pragma unroll
    for (int i = 0; i < 6; ++i) stage(i, bufN, 128);
    asm volatile("s_waitcnt vmcnt(6)" ::: "memory");
    __builtin_amdgcn_s_barrier();
    __builtin_amdgcn_sched_barrier(0);

    size_t kPre = 256;                 // byte k-offset of tile kt+2
#pragma unroll 1
    for (int kt = 0; kt < NT; ++kt) {
        const bool pf = (kt + 2 < NT);
        // 16 ds_read_b128 per wave: both k-slices (kk*64 elems) of this tile
        i32x4 af[2][4], bfr[2][4];
#pragma unroll
        for (int kk = 0; kk < 2; ++kk) {
#pragma unroll
            for (int mi = 0; mi < 4; ++mi) {
                int m = wm + mi * 16 + mr;
                af[kk][mi] = *(const i32x4*)(bufC + m * 128 +
                                             (((kk * 4 + q) ^ (m & 7)) * 16));
            }
#pragma unroll
            for (int ni = 0; ni < 4; ++ni) {
                int n = wn + ni * 16 + mr;
                bfr[kk][ni] = *(const i32x4*)(bufC + 16384 + n * 128 +
                                              (((kk * 4 + q) ^ (n & 7)) * 16));
            }
        }
        if (pf) {
#pragma unroll
            for (int i = 0; i < 6; ++i) stage(i, bufN2, kPre);
        }
        __builtin_amdgcn_s_setprio(1);
#pragma unroll
        for (int kk = 0; kk < 2; ++kk)
#pragma unroll
            for (int mi = 0; mi < 4; ++mi)
#pragma unroll
                for (int ni = 0; ni < 4; ++ni)
                    acc[mi][ni] = __builtin_amdgcn_mfma_i32_16x16x64_i8(
                        af[kk][mi], bfr[kk][ni], acc[mi][ni], 0, 0, 0);
        __builtin_amdgcn_s_setprio(0);
        if (pf)                    asm volatile("s_waitcnt vmcnt(6)" ::: "memory");
        else if (kt + 1 < NT)      asm volatile("s_waitcnt vmcnt(0)" ::: "memory");
        __builtin_amdgcn_s_barrier();
        __builtin_amdgcn_sched_barrier(0);
        signed char* t = bufC; bufC = bufN; bufN = bufN2; bufN2 = t;
        kPre += 128;
    }

    // C/D layout: col = lane&15, row = (lane>>4)*4 + reg (dtype-independent)
#pragma unroll
    for (int mi = 0; mi < 4; ++mi)
#pragma unroll
        for (int ni = 0; ni < 4; ++ni)
#pragma unroll
            for (int r = 0; r < 4; ++r) {
                int m = m0 + wm + mi * 16 + q * 4 + r;
                int n = n0 + wn + ni * 16 + mr;
                size_t off = (size_t)m * ldc + n;
                int v = acc[mi][ni][r];
                if (beta) v += C[off];
                C[off] = v;
            }
}

// ---------------- GEMM2 bf16 (R1-proven): C[m][n] = sum_k A[m][k]*B[n][k] --
template <int BM, int BN, int K, bool ACCUM>
__global__ __launch_bounds__(512, 2)
void gemm_nt(const unsigned short* __restrict__ Ag,
             const unsigned short* __restrict__ Bg,
             float* __restrict__ C, int ldc, int beta) {
    constexpr int BSZ = (BM + BN) * 64;          // elements per K-tile buffer
    constexpr int NA  = BM / 64;
    constexpr int NB  = BN / 64;
    constexpr int NT  = K / 64;
    static_assert(NA + NB == 6, "6 issues/K-tile assumed by vmcnt(6)");
    __shared__ __align__(16) unsigned short lds[3 * BSZ];   // 144 KiB

    const int tid  = threadIdx.x;
    const int wave = tid >> 6, lane = tid & 63;
    const int mr = lane & 15, q = lane >> 4;
    const int srow = tid >> 3, sslot = tid & 7;
    const int wm = (BM >= BN) ? (wave >> 1) * 64 : (wave & 1) * 64;
    const int wn = (BM >= BN) ? (wave & 1) * 64 : (wave >> 1) * 64;

    const int gx   = gridDim.x;
    const int nwg  = gx * gridDim.y;
    const int flat = blockIdx.y * gx + blockIdx.x;
    const int swz  = (flat & 7) * (nwg >> 3) + (flat >> 3);
    const int m0   = (swz % gx) * BM;
    const int n0   = (swz / gx) * BN;

    const char* aG = (const char*)Ag;
    const char* bG = (const char*)Bg;
    const int ssw = (sslot ^ (srow & 7)) * 16;
    size_t aoff[NA], boff[NB];
#pragma unroll
    for (int j = 0; j < NA; ++j)
        aoff[j] = (size_t)(m0 + j * 64 + srow) * (LDK * 2) + ssw;
#pragma unroll
    for (int j = 0; j < NB; ++j)
        boff[j] = (size_t)(n0 + j * 64 + srow) * (LDK * 2) + ssw;

    unsigned short* bufC  = lds;
    unsigned short* bufN  = lds + BSZ;
    unsigned short* bufN2 = lds + 2 * BSZ;

    auto stage = [&](int idx, unsigned short* buf, size_t kB) {
        if (idx < NA)
            gload16(aG + aoff[idx] + kB, buf + idx * 4096 + wave * 512);
        else
            gload16(bG + boff[idx - NA] + kB,
                    buf + BM * 64 + (idx - NA) * 4096 + wave * 512);
    };

    f32x4 acc[4][4];
#pragma unroll
    for (int a = 0; a < 4; ++a)
#pragma unroll
        for (int b = 0; b < 4; ++b) acc[a][b] = (f32x4){0.f, 0.f, 0.f, 0.f};

#pragma unroll
    for (int i = 0; i < 6; ++i) stage(i, bufC, 0);
#pragma unroll
    for (int i = 0; i < 6; ++i) stage(i, bufN, 128);
    asm volatile("s_waitcnt vmcnt(6)" ::: "memory");
    __builtin_amdgcn_s_barrier();
    __builtin_amdgcn_sched_barrier(0);

    size_t kPre = 256;
#pragma unroll 1
    for (int kt = 0; kt < NT; ++kt) {
        const bool pf = (kt + 2 < NT);
        bf16x8 af[2][4], bfr[2][4];
#pragma unroll
        for (int kk = 0; kk < 2; ++kk) {
#pragma unroll
            for (int mi = 0; mi < 4; ++mi) {
                int m = wm + mi * 16 + mr;
                af[kk][mi] = *(const bf16x8*)(bufC + m * 64 +
                                              (((kk * 4 + q) ^ (m & 7)) * 8));
            }
#pragma unroll
            for (int ni = 0; ni < 4; ++ni) {
                int n = wn + ni * 16 + mr;
                bfr[kk][ni] = *(const bf16x8*)(bufC + BM * 64 + n * 64 +
                                               (((kk * 4 + q) ^ (n & 7)) * 8));
            }
        }
        if (pf) {
#pragma unroll
            for (int i = 0; i < 6; ++i) stage(i, bufN2, kPre);
        }
        __builtin_amdgcn_s_setprio(1);
#pragma unroll
        for (int kk = 0; kk < 2; ++kk)
#pragma unroll
            for (int mi = 0; mi < 4; ++mi)
#pragma unroll
                for (int ni = 0; ni < 4; ++ni)
                    acc[mi][ni] = __builtin_amdgcn_mfma_f32_16x16x32_bf16(
                        af[kk][mi], bfr[kk][ni], acc[mi][ni], 0, 0, 0);
        __builtin_amdgcn_s_setprio(0);
        if (pf)                    asm volatile("s_waitcnt vmcnt(6)" ::: "memory");
        else if (kt + 1 < NT)      asm volatile("s_waitcnt vmcnt(0)" ::: "memory");
        __builtin_amdgcn_s_barrier();
        __builtin_amdgcn_sched_barrier(0);
        unsigned short* t = bufC; bufC = bufN; bufN = bufN2; bufN2 = t;
        kPre += 128;
    }

#pragma unroll
    for (int mi = 0; mi < 4; ++mi)
#pragma unroll
        for (int ni = 0; ni < 4; ++ni)
#pragma unroll
            for (int r = 0; r < 4; ++r) {
                int m = m0 + wm + mi * 16 + q * 4 + r;
                int n = n0 + wn + ni * 16 + mr;
                size_t off = (size_t)m * ldc + n;
                float v = acc[mi][ni][r];
                if (ACCUM) { if (beta) v += C[off]; }
                C[off] = v;
            }
}

// ---------------- MT i32 -> bf16 (dequant by 1/127^2) ----------------
__global__ __launch_bounds__(256)
void cvt(const int* __restrict__ src, unsigned short* __restrict__ dst) {
    int idx = blockIdx.x * 256 + threadIdx.x;
    int4 v = ((const int4*)src)[idx];
    ushort4 o;
    o.x = f2bf((float)v.x * INV_Q2); o.y = f2bf((float)v.y * INV_Q2);
    o.z = f2bf((float)v.z * INV_Q2); o.w = f2bf((float)v.w * INV_Q2);
    ((ushort4*)dst)[idx] = o;
}

// ---------------- epilogue: re/im, row norm, scale (in place on d_out) ----
__global__ __launch_bounds__(256)
void epi(float* __restrict__ out, const float* __restrict__ pts,
         const float* __restrict__ A) {
    int n = blockIdx.x;
    int t = threadIdx.x;
    float x0 = pts[n * 3 + 0], x1 = pts[n * 3 + 1], x2 = pts[n * 3 + 2];
    float* row = out + (size_t)n * JD;
    float reA[2], imA[2];
    float ssum = 0.f;
#pragma unroll
    for (int u = 0; u < 2; ++u) {
        int j = t + u * 256;
        float pa = (x0 * A[j] + x1 * A[ENC + j] + x2 * A[2 * ENC + j]) * INV_R;
        float s, c;
        sincos_rev(pa, &s, &c);
        float gc = row[j], gs = row[ENC + j];
        float re = gc * c + gs * s;
        float im = gs * c - gc * s;
        reA[u] = re; imA[u] = im;
        ssum += re * re + im * im;
    }
#pragma unroll
    for (int off = 32; off > 0; off >>= 1) ssum += __shfl_down(ssum, off);
    __shared__ float red[4];
    if ((t & 63) == 0) red[t >> 6] = ssum;
    __syncthreads();
    float tot = red[0] + red[1] + red[2] + red[3];
    float scale = SQRT_D / sqrtf(tot);
#pragma unroll
    for (int u = 0; u < 2; ++u) {
        int j = t + u * 256;
        row[j]       = reA[u] * scale;
        row[ENC + j] = imA[u] * scale;
    }
}

extern "C" void kernel_launch(void* const* d_in, const int* in_sizes, int n_in,
                              void* d_out, int out_size, void* d_ws, size_t ws_size,
                              hipStream_t stream) {
    const float* pts = (const float*)d_in[0];
    const float* A   = (const float*)d_in[1];
    const float* B   = (const float*)d_in[2];
    float* out = (float*)d_out;
    char* ws = (char*)d_ws;

    // ws layout (176 MiB high-water):
    //   phase A: [0, 8M)    eAT8 [1024][8192] i8
    //            [8M, 72M)  eBT8 [8192][8192] i8
    //   phase C: [0, 128M)  eBw  [8192][8192] bf16 (overlaps dead eAT8/eBT8)
    //   [128M, 160M)        MTi  [1024][8192] i32  (dead after cvt)
    //   [160M, 176M)        MTb  [1024][8192] bf16
    signed char*    eAT8 = (signed char*)ws;
    signed char*    eBT8 = (signed char*)(ws + ((size_t)8 << 20));
    unsigned short* eBw  = (unsigned short*)ws;
    int*            MTi  = (int*)(ws + ((size_t)128 << 20));
    unsigned short* MTb  = (unsigned short*)(ws + ((size_t)160 << 20));

    for (int c = 0; c < NCH; ++c) {
        gen_t<<<dim3(73728), 256, 0, stream>>>(pts, A, B, eAT8, eBT8, c * CH);
        // MTi[j][i] += eAT8[j][:] . eBT8[i][:]  (M=1024, N=8192 -> 8x32 WGs)
        gemm_i8<<<dim3(8, 32), 512, 0, stream>>>(eAT8, eBT8, MTi, ID, c);
    }
    cvt<<<dim3(8192), 256, 0, stream>>>(MTi, MTb);
    for (int c = 0; c < NCH; ++c) {
        gen_b<<<dim3(65536), 256, 0, stream>>>(pts, B, eBw, c * CH);
        // G[ln][j] = eB[ln][:] . MTb[j][:]   (M=8192, N=1024 -> 32x8 WGs)
        gemm_nt<256, 128, ID, false><<<dim3(32, 8), 512, 0, stream>>>(
            eBw, MTb, out + (size_t)c * CH * JD, JD, 0);
    }
    epi<<<dim3(NPTS), 256, 0, stream>>>(out, pts, A);
}